// Round 4
// baseline (552.732 us; speedup 1.0000x reference)
//
#include <hip/hip_runtime.h>
#include <hip/hip_bf16.h>
#include <math.h>

// MessagePassingLayer on MI355X — round 4.
// vs round 3: (a) prep_weights rewritten as tiled LDS transpose, 36 blocks,
// coalesced float4 reads + int4 writes (was 9 blocks of stride-512B scalar
// gathers — suspected ~100µs hidden sink). (b) edge_fused barriers 7->6:
// gate-partial visibility barrier merged with the stage-1 "A-buffer reads
// drained" barrier. (c) first weight LDB hoisted above B1.

typedef __bf16 bf16x8 __attribute__((ext_vector_type(8)));
typedef float floatx4 __attribute__((ext_vector_type(4)));

#define LN_EPS 1e-5f

__device__ __forceinline__ unsigned short f2bf(float x) {
  unsigned int u = __float_as_uint(x);
  u = u + 0x7fffu + ((u >> 16) & 1u);
  return (unsigned short)(u >> 16);
}

__device__ __forceinline__ float geluf(float x) {
  // tanh-form gelu via sigmoid: 0.5x(1+tanh(a)) = x*sigmoid(2a),
  // 2a = 1.5957691x(1 + 0.044715x^2). |err| ~3e-3 vs erf-gelu.
  float t = x * x;
  float u = x * (1.5957691216f + 0.0713548162f * t);
  return x / (1.0f + __expf(-u));
}

// ---------------------------------------------------------------------------
// prep: 9 [128,128] fp32 weights -> bf16 [n][k] (transposed). Tiled LDS
// transpose: 36 blocks = 9 matrices x 4 k-chunks of 32 rows. Coalesced
// float4 reads, int4 writes. slots: 0 WsrcT 1 WdstT 2 W1aT 3 W1bT 4 W2T
// 5 W3T 6 Wg1aT 7 Wg1bT 8 WoutT
// ---------------------------------------------------------------------------
__global__ __launch_bounds__(256) void prep_weights(
    const float* w0, const float* w1, const float* w2, const float* w3,
    const float* w4, const float* w5, const float* w6, const float* w7,
    const float* w8, unsigned short* out) {
  const float* srcs[9] = {w0, w1, w2, w3, w4, w5, w6, w7, w8};
  int m = blockIdx.x >> 2, c = blockIdx.x & 3;
  const float* src = srcs[m] + c * 32 * 128;  // rows k in [32c, 32c+32)
  __shared__ unsigned short sT[128][35];      // [n][krel], pad 35 vs conflicts
  int tid = threadIdx.x;

  for (int it = 0; it < 4; ++it) {  // 1024 float4s = 4096 floats
    int f4 = tid + it * 256;
    float4 v = ((const float4*)src)[f4];
    int krel = f4 >> 5;          // (f4*4)/128
    int n0 = (f4 & 31) * 4;
    sT[n0 + 0][krel] = f2bf(v.x);
    sT[n0 + 1][krel] = f2bf(v.y);
    sT[n0 + 2][krel] = f2bf(v.z);
    sT[n0 + 3][krel] = f2bf(v.w);
  }
  __syncthreads();
  unsigned short* dst = out + m * 16384 + c * 32;
  for (int it = 0; it < 2; ++it) {  // 512 chunks of 8 halfwords
    int ch = tid + it * 256;
    int n = ch >> 2, kc = (ch & 3) * 8;
    unsigned short tmp[8];
    for (int j = 0; j < 8; ++j) tmp[j] = sT[n][kc + j];
    *(int4*)(dst + n * 128 + kc) = *(const int4*)tmp;
  }
}

// B-fragment loader: wave w, lane (lr,q) needs rows 32w+lr and 32w+16+lr,
// cols kb*32+q*8..+8 of the [n][k] bf16 matrix. 8 x 16B loads from L2.
#define LDB(pB, B)                                              \
  do {                                                          \
    const unsigned short* _p = (pB);                            \
    for (int kb = 0; kb < 4; ++kb) {                            \
      B[0][kb] = *(const bf16x8*)(_p + kb * 32);                \
      B[1][kb] = *(const bf16x8*)(_p + 2048 + kb * 32);         \
    }                                                           \
  } while (0)

// ---------------------------------------------------------------------------
// Fused node GEMM: src_h = feat@Wsrc+b_src, dst_h = feat@Wdst+b_dst (bf16 out).
// ---------------------------------------------------------------------------
__global__ __launch_bounds__(256, 4) void gemm_node(
    const float* __restrict__ A, const unsigned short* __restrict__ wT,
    const float* __restrict__ b_src, const float* __restrict__ b_dst,
    unsigned short* __restrict__ src_h, unsigned short* __restrict__ dst_h,
    int M) {
  __shared__ __align__(16) unsigned short sA[64][136];
  int tid = threadIdx.x;
  int r0 = blockIdx.x * 64;

  {
    int r = tid >> 2, seg = tid & 3;
    int row = r0 + r;
    const float* src = A + (long long)row * 128;
    for (int it = 0; it < 4; ++it) {
      int c = (seg * 4 + it) * 8;
      unsigned short tmp[8];
      if (row < M) {
        float4 f0 = *(const float4*)(src + c);
        float4 f1 = *(const float4*)(src + c + 4);
        tmp[0] = f2bf(f0.x); tmp[1] = f2bf(f0.y); tmp[2] = f2bf(f0.z); tmp[3] = f2bf(f0.w);
        tmp[4] = f2bf(f1.x); tmp[5] = f2bf(f1.y); tmp[6] = f2bf(f1.z); tmp[7] = f2bf(f1.w);
      } else {
        for (int j = 0; j < 8; ++j) tmp[j] = 0;
      }
      *(int4*)&sA[r][c] = *(const int4*)tmp;
    }
  }
  __syncthreads();

  int w = tid >> 6, lane = tid & 63, lr = lane & 15, q = lane >> 4;
  const unsigned short* pB = wT + (32 * w + lr) * 128 + q * 8;

  bf16x8 B[2][4];
  floatx4 acc[4][2];

  for (int pass = 0; pass < 2; ++pass) {
    LDB(pB + pass * 16384, B);
    for (int mb = 0; mb < 4; ++mb)
      for (int nb = 0; nb < 2; ++nb) acc[mb][nb] = (floatx4){0.f, 0.f, 0.f, 0.f};
    for (int kb = 0; kb < 4; ++kb) {
      int k = kb * 32 + q * 8;
      for (int mb = 0; mb < 4; ++mb) {
        bf16x8 a = *(const bf16x8*)&sA[16 * mb + lr][k];
        acc[mb][0] = __builtin_amdgcn_mfma_f32_16x16x32_bf16(a, B[0][kb], acc[mb][0], 0, 0, 0);
        acc[mb][1] = __builtin_amdgcn_mfma_f32_16x16x32_bf16(a, B[1][kb], acc[mb][1], 0, 0, 0);
      }
    }
    const float* bias = pass ? b_dst : b_src;
    unsigned short* C = pass ? dst_h : src_h;
    float bv0 = bias[32 * w + lr], bv1 = bias[32 * w + 16 + lr];
    for (int mb = 0; mb < 4; ++mb)
      for (int i = 0; i < 4; ++i) {
        int row = r0 + 16 * mb + 4 * q + i;
        if (row < M) {
          long long base = (long long)row * 128 + 32 * w + lr;
          C[base] = f2bf(acc[mb][0][i] + bv0);
          C[base + 16] = f2bf(acc[mb][1][i] + bv1);
        }
      }
  }
}

// ---------------------------------------------------------------------------
// out GEMM: d_out = upd@Wout + b_out (fp32 in, fp32 out)
// ---------------------------------------------------------------------------
__global__ __launch_bounds__(256, 4) void gemm_out(
    const float* __restrict__ A, const unsigned short* __restrict__ Bt,
    const float* __restrict__ bias, float* __restrict__ C, int M) {
  __shared__ __align__(16) unsigned short sA[64][136];
  int tid = threadIdx.x;
  int r0 = blockIdx.x * 64;

  {
    int r = tid >> 2, seg = tid & 3;
    int row = r0 + r;
    const float* src = A + (long long)row * 128;
    for (int it = 0; it < 4; ++it) {
      int c = (seg * 4 + it) * 8;
      unsigned short tmp[8];
      if (row < M) {
        float4 f0 = *(const float4*)(src + c);
        float4 f1 = *(const float4*)(src + c + 4);
        tmp[0] = f2bf(f0.x); tmp[1] = f2bf(f0.y); tmp[2] = f2bf(f0.z); tmp[3] = f2bf(f0.w);
        tmp[4] = f2bf(f1.x); tmp[5] = f2bf(f1.y); tmp[6] = f2bf(f1.z); tmp[7] = f2bf(f1.w);
      } else {
        for (int j = 0; j < 8; ++j) tmp[j] = 0;
      }
      *(int4*)&sA[r][c] = *(const int4*)tmp;
    }
  }
  __syncthreads();

  int w = tid >> 6, lane = tid & 63, lr = lane & 15, q = lane >> 4;
  const unsigned short* pB = Bt + (32 * w + lr) * 128 + q * 8;

  bf16x8 B[2][4];
  LDB(pB, B);
  floatx4 acc[4][2];
  for (int mb = 0; mb < 4; ++mb)
    for (int nb = 0; nb < 2; ++nb) acc[mb][nb] = (floatx4){0.f, 0.f, 0.f, 0.f};
  for (int kb = 0; kb < 4; ++kb) {
    int k = kb * 32 + q * 8;
    for (int mb = 0; mb < 4; ++mb) {
      bf16x8 a = *(const bf16x8*)&sA[16 * mb + lr][k];
      acc[mb][0] = __builtin_amdgcn_mfma_f32_16x16x32_bf16(a, B[0][kb], acc[mb][0], 0, 0, 0);
      acc[mb][1] = __builtin_amdgcn_mfma_f32_16x16x32_bf16(a, B[1][kb], acc[mb][1], 0, 0, 0);
    }
  }
  float bv0 = bias[32 * w + lr], bv1 = bias[32 * w + 16 + lr];
  for (int mb = 0; mb < 4; ++mb)
    for (int i = 0; i < 4; ++i) {
      int row = r0 + 16 * mb + 4 * q + i;
      if (row < M) {
        long long base = (long long)row * 128 + 32 * w + lr;
        C[base] = acc[mb][0][i] + bv0;
        C[base + 16] = acc[mb][1][i] + bv1;
      }
    }
}

// ---------------------------------------------------------------------------
// Fused edge kernel: 64 edges/block, 4 waves; wave w owns cols [32w,32w+32).
// 6 barriers. LDS ~38KB -> 4 blocks/CU.
// ---------------------------------------------------------------------------
__global__ __launch_bounds__(256, 4) void edge_fused(
    const unsigned short* __restrict__ src_h, const unsigned short* __restrict__ dst_h,
    const int* __restrict__ edge_src, const int* __restrict__ edge_dst,
    const unsigned short* __restrict__ wT,
    const float* __restrict__ b1, const float* __restrict__ b2,
    const float* __restrict__ b3, const float* __restrict__ ln_g,
    const float* __restrict__ ln_b, const float* __restrict__ bg1,
    const float* __restrict__ Wg2, const float* __restrict__ bg2,
    float* __restrict__ upd, int E) {
  __shared__ __align__(16) unsigned short sSE[64][136];  // se, later h1
  __shared__ __align__(16) unsigned short sDE[64][136];  // de, later h2
  __shared__ int sDst[64];
  __shared__ float sGate[64];
  __shared__ float sR1[4][64];
  __shared__ float sR2[4][64];
  __shared__ float sM[64];
  __shared__ float sRS[64];

  int tid = threadIdx.x;
  int e0 = blockIdx.x * 64;
  int w = tid >> 6, lane = tid & 63, lr = lane & 15, q = lane >> 4;
  const unsigned short* pB = wT + (32 * w + lr) * 128 + q * 8;

  bf16x8 B[2][4];
  LDB(pB + 6 * 16384, B);  // Wg1a in flight before the gather/barrier

  {  // gather se/de rows (bf16, 256B each) — 4 threads per edge row
    int r = tid >> 2, seg = tid & 3;
    int e = e0 + r;
    int ee = (e < E) ? e : (E - 1);
    int es = edge_src[ee], ed = edge_dst[ee];
    if (seg == 0) sDst[r] = (e < E) ? ed : -1;
    const int4* ps = (const int4*)(src_h + (long long)es * 128);
    const int4* pd = (const int4*)(dst_h + (long long)ed * 128);
    for (int it = 0; it < 4; ++it) {
      int cc = seg * 4 + it;
      *(int4*)&sSE[r][cc * 8] = ps[cc];
      *(int4*)&sDE[r][cc * 8] = pd[cc];
    }
  }

  auto pass = [&](const unsigned short (*Ab)[136], floatx4 (&acc)[4][2]) {
    for (int kb = 0; kb < 4; ++kb) {
      int k = kb * 32 + q * 8;
      for (int mb = 0; mb < 4; ++mb) {
        bf16x8 a = *(const bf16x8*)&Ab[16 * mb + lr][k];
        acc[mb][0] = __builtin_amdgcn_mfma_f32_16x16x32_bf16(a, B[0][kb], acc[mb][0], 0, 0, 0);
        acc[mb][1] = __builtin_amdgcn_mfma_f32_16x16x32_bf16(a, B[1][kb], acc[mb][1], 0, 0, 0);
      }
    }
  };

  __syncthreads();  // B1: gather visible

  // ---- gate path: accg = se@Wg1a + de@Wg1b ----
  floatx4 accg[4][2];
  for (int mb = 0; mb < 4; ++mb)
    for (int nb = 0; nb < 2; ++nb) accg[mb][nb] = (floatx4){0.f, 0.f, 0.f, 0.f};
  pass(sSE, accg);
  LDB(pB + 7 * 16384, B);
  pass(sDE, accg);

  {  // partial dot with Wg2 (gelu applied), reduce over lr within each quad
    float wg0 = Wg2[32 * w + lr], wg1 = Wg2[32 * w + 16 + lr];
    float bgv0 = bg1[32 * w + lr], bgv1 = bg1[32 * w + 16 + lr];
    for (int mb = 0; mb < 4; ++mb)
      for (int i = 0; i < 4; ++i) {
        float p = geluf(accg[mb][0][i] + bgv0) * wg0 +
                  geluf(accg[mb][1][i] + bgv1) * wg1;
        p += __shfl_xor(p, 1); p += __shfl_xor(p, 2);
        p += __shfl_xor(p, 4); p += __shfl_xor(p, 8);
        if (lr == 0) sR1[w][16 * mb + 4 * q + i] = p;
      }
  }

  // ---- stage 1 MFMAs (before the barrier; partials ride along) ----
  floatx4 acc1[4][2];
  for (int mb = 0; mb < 4; ++mb)
    for (int nb = 0; nb < 2; ++nb) acc1[mb][nb] = (floatx4){0.f, 0.f, 0.f, 0.f};
  LDB(pB + 2 * 16384, B);
  pass(sSE, acc1);
  LDB(pB + 3 * 16384, B);
  pass(sDE, acc1);

  __syncthreads();  // B2: gate partials visible AND all sSE/sDE reads drained

  if (tid < 64) {
    float g = sR1[0][tid] + sR1[1][tid] + sR1[2][tid] + sR1[3][tid] + bg2[0];
    sGate[tid] = 1.f / (1.f + __expf(-g));
  }
  {  // h1 -> sSE
    float bv0 = b1[32 * w + lr], bv1 = b1[32 * w + 16 + lr];
    for (int mb = 0; mb < 4; ++mb)
      for (int i = 0; i < 4; ++i) {
        int r = 16 * mb + 4 * q + i;
        sSE[r][32 * w + lr] = f2bf(geluf(acc1[mb][0][i] + bv0));
        sSE[r][32 * w + 16 + lr] = f2bf(geluf(acc1[mb][1][i] + bv1));
      }
  }
  __syncthreads();  // B3: h1 + sGate visible

  // ---- stage 2: h2 = gelu(h1@W2 + b2) ----
  floatx4 acc2[4][2];
  for (int mb = 0; mb < 4; ++mb)
    for (int nb = 0; nb < 2; ++nb) acc2[mb][nb] = (floatx4){0.f, 0.f, 0.f, 0.f};
  LDB(pB + 4 * 16384, B);
  pass(sSE, acc2);
  {  // h2 -> sDE (last sDE read was before B2)
    float bv0 = b2[32 * w + lr], bv1 = b2[32 * w + 16 + lr];
    for (int mb = 0; mb < 4; ++mb)
      for (int i = 0; i < 4; ++i) {
        int r = 16 * mb + 4 * q + i;
        sDE[r][32 * w + lr] = f2bf(geluf(acc2[mb][0][i] + bv0));
        sDE[r][32 * w + 16 + lr] = f2bf(geluf(acc2[mb][1][i] + bv1));
      }
  }
  __syncthreads();  // B4: h2 visible

  // ---- stage 3: x = h2@W3 + b3 ; layernorm ; gate ; scatter ----
  floatx4 acc3[4][2];
  for (int mb = 0; mb < 4; ++mb)
    for (int nb = 0; nb < 2; ++nb) acc3[mb][nb] = (floatx4){0.f, 0.f, 0.f, 0.f};
  LDB(pB + 5 * 16384, B);
  pass(sDE, acc3);
  {
    float bv0 = b3[32 * w + lr], bv1 = b3[32 * w + 16 + lr];
    for (int mb = 0; mb < 4; ++mb)
      for (int i = 0; i < 4; ++i) {
        float x0 = acc3[mb][0][i] + bv0;
        float x1 = acc3[mb][1][i] + bv1;
        acc3[mb][0][i] = x0; acc3[mb][1][i] = x1;
        float s = x0 + x1, s2 = x0 * x0 + x1 * x1;
        s += __shfl_xor(s, 1); s += __shfl_xor(s, 2);
        s += __shfl_xor(s, 4); s += __shfl_xor(s, 8);
        s2 += __shfl_xor(s2, 1); s2 += __shfl_xor(s2, 2);
        s2 += __shfl_xor(s2, 4); s2 += __shfl_xor(s2, 8);
        if (lr == 0) { sR1[w][16 * mb + 4 * q + i] = s; sR2[w][16 * mb + 4 * q + i] = s2; }
      }
  }
  __syncthreads();  // B5: LN partials visible (sR1 reuse safe: last read pre-B3)
  if (tid < 64) {
    float s = sR1[0][tid] + sR1[1][tid] + sR1[2][tid] + sR1[3][tid];
    float s2 = sR2[0][tid] + sR2[1][tid] + sR2[2][tid] + sR2[3][tid];
    float m = s * (1.f / 128.f);
    float v = s2 * (1.f / 128.f) - m * m;
    sM[tid] = m;
    sRS[tid] = rsqrtf(v + LN_EPS);
  }
  __syncthreads();  // B6: stats visible
  {
    float lg0 = ln_g[32 * w + lr], lg1 = ln_g[32 * w + 16 + lr];
    float lb0 = ln_b[32 * w + lr], lb1 = ln_b[32 * w + 16 + lr];
    for (int mb = 0; mb < 4; ++mb)
      for (int i = 0; i < 4; ++i) {
        int r = 16 * mb + 4 * q + i;
        int dst = sDst[r];
        if (dst >= 0) {
          float m = sM[r], rs = sRS[r], gt = sGate[r];
          float v0 = ((acc3[mb][0][i] - m) * rs * lg0 + lb0) * gt;
          float v1 = ((acc3[mb][1][i] - m) * rs * lg1 + lb1) * gt;
          float* base = upd + (long long)dst * 128;
          unsafeAtomicAdd(base + 32 * w + lr, v0);
          unsafeAtomicAdd(base + 32 * w + 16 + lr, v1);
        }
      }
  }
}

// ---------------------------------------------------------------------------
extern "C" void kernel_launch(void* const* d_in, const int* in_sizes, int n_in,
                              void* d_out, int out_size, void* d_ws, size_t ws_size,
                              hipStream_t stream) {
  const float* feat   = (const float*)d_in[0];
  const int* edge_src = (const int*)d_in[1];
  const int* edge_dst = (const int*)d_in[2];
  const float* W_src = (const float*)d_in[3];  const float* b_src = (const float*)d_in[4];
  const float* W_dst = (const float*)d_in[5];  const float* b_dst = (const float*)d_in[6];
  const float* W1a = (const float*)d_in[7];    const float* W1b = (const float*)d_in[8];
  const float* b1  = (const float*)d_in[9];
  const float* W2  = (const float*)d_in[10];   const float* b2  = (const float*)d_in[11];
  const float* W3  = (const float*)d_in[12];   const float* b3  = (const float*)d_in[13];
  const float* ln_g = (const float*)d_in[14];  const float* ln_b = (const float*)d_in[15];
  const float* Wg1a = (const float*)d_in[16];  const float* Wg1b = (const float*)d_in[17];
  const float* bg1  = (const float*)d_in[18];
  const float* Wg2  = (const float*)d_in[19];  const float* bg2 = (const float*)d_in[20];
  const float* W_out = (const float*)d_in[21]; const float* b_out = (const float*)d_in[22];

  int N = in_sizes[0] / 128;   // 100000
  int E = in_sizes[1];         // 400000

  // workspace layout (bytes): [wT 9*32KB][src_h bf16][dst_h bf16][upd fp32]
  char* ws = (char*)d_ws;
  unsigned short* wT = (unsigned short*)ws;
  size_t off = 9 * 16384 * sizeof(unsigned short);
  unsigned short* src_h = (unsigned short*)(ws + off);
  off += (size_t)N * 128 * sizeof(unsigned short);
  unsigned short* dst_h = (unsigned short*)(ws + off);
  off += (size_t)N * 128 * sizeof(unsigned short);
  float* upd = (float*)(ws + off);

  (void)hipMemsetAsync(upd, 0, (size_t)N * 128 * sizeof(float), stream);
  prep_weights<<<36, 256, 0, stream>>>(W_src, W_dst, W1a, W1b, W2, W3, Wg1a, Wg1b,
                                       W_out, wT);
  int mtiles = (N + 63) / 64;
  gemm_node<<<mtiles, 256, 0, stream>>>(feat, wT, b_src, b_dst, src_h, dst_h, N);
  edge_fused<<<(E + 63) / 64, 256, 0, stream>>>(src_h, dst_h, edge_src, edge_dst, wT,
                                                b1, b2, b3, ln_g, ln_b, bg1, Wg2, bg2,
                                                upd, E);
  gemm_out<<<mtiles, 256, 0, stream>>>(upd, wT + 8 * 16384, b_out, (float*)d_out, N);
}

// Round 5
// 485.105 us; speedup vs baseline: 1.1394x; 1.1394x over previous
//
#include <hip/hip_runtime.h>
#include <hip/hip_bf16.h>
#include <math.h>

// MessagePassingLayer on MI355X — round 5.
// Gather-side algebra: se@W1a = (src_h@W1a)[edge_src], so the first-layer
// edge GEMMs (W1a,W1b,Wg1a,Wg1b) move to node level. node_fused computes
// SrcCat=[src_h@W1a+b1 | src_h@Wg1a+bg1], DstCat=[dst_h@W1b | dst_h@Wg1b]
// ([N,256] bf16 each) chaining through LDS (src_h/dst_h never hit HBM).
// edge_fused: gather 2x512B rows, h1=gelu(sum) + gate partial-dot during
// gather, then just 2 MFMA passes (W2,W3) + LN + atomic scatter. 4 barriers.
// Round-3 memory ordering restored (round 4's hoist/merge tripled traffic).

typedef __bf16 bf16x8 __attribute__((ext_vector_type(8)));
typedef float floatx4 __attribute__((ext_vector_type(4)));

#define LN_EPS 1e-5f

__device__ __forceinline__ unsigned short f2bf(float x) {
  unsigned int u = __float_as_uint(x);
  u = u + 0x7fffu + ((u >> 16) & 1u);
  return (unsigned short)(u >> 16);
}

__device__ __forceinline__ float bf2f(unsigned short s) {
  return __uint_as_float(((unsigned int)s) << 16);
}

__device__ __forceinline__ float geluf(float x) {
  // tanh-form gelu via sigmoid; |err| ~3e-3 vs erf-gelu, inside budget.
  float t = x * x;
  float u = x * (1.5957691216f + 0.0713548162f * t);
  return x / (1.0f + __expf(-u));
}

// ---------------------------------------------------------------------------
// prep: 9 [128,128] fp32 weights -> bf16 [n][k] (transposed). Tiled LDS
// transpose, 36 blocks. slots: 0 WsrcT 1 WdstT 2 W1aT 3 W1bT 4 W2T 5 W3T
// 6 Wg1aT 7 Wg1bT 8 WoutT
// ---------------------------------------------------------------------------
__global__ __launch_bounds__(256) void prep_weights(
    const float* w0, const float* w1, const float* w2, const float* w3,
    const float* w4, const float* w5, const float* w6, const float* w7,
    const float* w8, unsigned short* out) {
  const float* srcs[9] = {w0, w1, w2, w3, w4, w5, w6, w7, w8};
  int m = blockIdx.x >> 2, c = blockIdx.x & 3;
  const float* src = srcs[m] + c * 32 * 128;
  __shared__ unsigned short sT[128][35];
  int tid = threadIdx.x;

  for (int it = 0; it < 4; ++it) {
    int f4 = tid + it * 256;
    float4 v = ((const float4*)src)[f4];
    int krel = f4 >> 5;
    int n0 = (f4 & 31) * 4;
    sT[n0 + 0][krel] = f2bf(v.x);
    sT[n0 + 1][krel] = f2bf(v.y);
    sT[n0 + 2][krel] = f2bf(v.z);
    sT[n0 + 3][krel] = f2bf(v.w);
  }
  __syncthreads();
  unsigned short* dst = out + m * 16384 + c * 32;
  for (int it = 0; it < 2; ++it) {
    int ch = tid + it * 256;
    int n = ch >> 2, kc = (ch & 3) * 8;
    unsigned short tmp[8];
    for (int j = 0; j < 8; ++j) tmp[j] = sT[n][kc + j];
    *(int4*)(dst + n * 128 + kc) = *(const int4*)tmp;
  }
}

// B-fragment loader: wave w, lane (lr,q): rows 32w+lr, 32w+16+lr; cols
// kb*32+q*8..+8 of the [n][k] bf16 matrix.
#define LDB(pB, B)                                              \
  do {                                                          \
    const unsigned short* _p = (pB);                            \
    for (int kb = 0; kb < 4; ++kb) {                            \
      B[0][kb] = *(const bf16x8*)(_p + kb * 32);                \
      B[1][kb] = *(const bf16x8*)(_p + 2048 + kb * 32);         \
    }                                                           \
  } while (0)

// ---------------------------------------------------------------------------
// node_fused: per 64-row tile of feat, compute
//   src_h = feat@Wsrc+b_src (LDS) ; SrcCat = [src_h@W1a+b1 | src_h@Wg1a+bg1]
//   dst_h = feat@Wdst+b_dst (LDS) ; DstCat = [dst_h@W1b | dst_h@Wg1b]
// ---------------------------------------------------------------------------
__global__ __launch_bounds__(256, 4) void node_fused(
    const float* __restrict__ feat, const unsigned short* __restrict__ wT,
    const float* __restrict__ b_src, const float* __restrict__ b_dst,
    const float* __restrict__ b1, const float* __restrict__ bg1,
    unsigned short* __restrict__ SrcCat, unsigned short* __restrict__ DstCat,
    int M) {
  __shared__ __align__(16) unsigned short sF[64][136];  // feat bf16
  __shared__ __align__(16) unsigned short sT[64][136];  // src/dst tile bf16
  int tid = threadIdx.x;
  int r0 = blockIdx.x * 64;

  {  // stage feat
    int r = tid >> 2, seg = tid & 3;
    int row = r0 + r;
    const float* src = feat + (long long)row * 128;
    for (int it = 0; it < 4; ++it) {
      int c = (seg * 4 + it) * 8;
      unsigned short tmp[8];
      if (row < M) {
        float4 f0 = *(const float4*)(src + c);
        float4 f1 = *(const float4*)(src + c + 4);
        tmp[0] = f2bf(f0.x); tmp[1] = f2bf(f0.y); tmp[2] = f2bf(f0.z); tmp[3] = f2bf(f0.w);
        tmp[4] = f2bf(f1.x); tmp[5] = f2bf(f1.y); tmp[6] = f2bf(f1.z); tmp[7] = f2bf(f1.w);
      } else {
        for (int j = 0; j < 8; ++j) tmp[j] = 0;
      }
      *(int4*)&sF[r][c] = *(const int4*)tmp;
    }
  }
  __syncthreads();  // B1: feat staged

  int w = tid >> 6, lane = tid & 63, lr = lane & 15, q = lane >> 4;
  const unsigned short* pB = wT + (32 * w + lr) * 128 + q * 8;

  bf16x8 B[2][4];
  floatx4 acc[4][2];

  auto zacc = [&]() {
    for (int mb = 0; mb < 4; ++mb)
      for (int nb = 0; nb < 2; ++nb) acc[mb][nb] = (floatx4){0.f, 0.f, 0.f, 0.f};
  };
  auto pass = [&](const unsigned short (*Ab)[136]) {
    for (int kb = 0; kb < 4; ++kb) {
      int k = kb * 32 + q * 8;
      for (int mb = 0; mb < 4; ++mb) {
        bf16x8 a = *(const bf16x8*)&Ab[16 * mb + lr][k];
        acc[mb][0] = __builtin_amdgcn_mfma_f32_16x16x32_bf16(a, B[0][kb], acc[mb][0], 0, 0, 0);
        acc[mb][1] = __builtin_amdgcn_mfma_f32_16x16x32_bf16(a, B[1][kb], acc[mb][1], 0, 0, 0);
      }
    }
  };
  auto toLDS = [&](const float* bias) {  // acc + bias -> sT (bf16)
    float bv0 = bias[32 * w + lr], bv1 = bias[32 * w + 16 + lr];
    for (int mb = 0; mb < 4; ++mb)
      for (int i = 0; i < 4; ++i) {
        int r = 16 * mb + 4 * q + i;
        sT[r][32 * w + lr] = f2bf(acc[mb][0][i] + bv0);
        sT[r][32 * w + 16 + lr] = f2bf(acc[mb][1][i] + bv1);
      }
  };
  auto toGlobal = [&](unsigned short* dst, float bv0, float bv1, int half) {
    for (int mb = 0; mb < 4; ++mb)
      for (int i = 0; i < 4; ++i) {
        int row = r0 + 16 * mb + 4 * q + i;
        if (row < M) {
          long long base = (long long)row * 256 + half + 32 * w + lr;
          dst[base] = f2bf(acc[mb][0][i] + bv0);
          dst[base + 16] = f2bf(acc[mb][1][i] + bv1);
        }
      }
  };

  // ---- src chain ----
  LDB(pB + 0 * 16384, B); zacc(); pass(sF); toLDS(b_src);
  __syncthreads();  // B2: src tile visible
  LDB(pB + 2 * 16384, B); zacc(); pass(sT);
  toGlobal(SrcCat, b1[32 * w + lr], b1[32 * w + 16 + lr], 0);
  LDB(pB + 6 * 16384, B); zacc(); pass(sT);
  toGlobal(SrcCat, bg1[32 * w + lr], bg1[32 * w + 16 + lr], 128);
  __syncthreads();  // B3: sT reads drained

  // ---- dst chain ----
  LDB(pB + 1 * 16384, B); zacc(); pass(sF); toLDS(b_dst);
  __syncthreads();  // B4: dst tile visible
  LDB(pB + 3 * 16384, B); zacc(); pass(sT);
  toGlobal(DstCat, 0.f, 0.f, 0);
  LDB(pB + 7 * 16384, B); zacc(); pass(sT);
  toGlobal(DstCat, 0.f, 0.f, 128);
}

// ---------------------------------------------------------------------------
// out GEMM: d_out = upd@Wout + b_out (fp32 in, fp32 out)
// ---------------------------------------------------------------------------
__global__ __launch_bounds__(256, 4) void gemm_out(
    const float* __restrict__ A, const unsigned short* __restrict__ Bt,
    const float* __restrict__ bias, float* __restrict__ C, int M) {
  __shared__ __align__(16) unsigned short sA[64][136];
  int tid = threadIdx.x;
  int r0 = blockIdx.x * 64;

  {
    int r = tid >> 2, seg = tid & 3;
    int row = r0 + r;
    const float* src = A + (long long)row * 128;
    for (int it = 0; it < 4; ++it) {
      int c = (seg * 4 + it) * 8;
      unsigned short tmp[8];
      if (row < M) {
        float4 f0 = *(const float4*)(src + c);
        float4 f1 = *(const float4*)(src + c + 4);
        tmp[0] = f2bf(f0.x); tmp[1] = f2bf(f0.y); tmp[2] = f2bf(f0.z); tmp[3] = f2bf(f0.w);
        tmp[4] = f2bf(f1.x); tmp[5] = f2bf(f1.y); tmp[6] = f2bf(f1.z); tmp[7] = f2bf(f1.w);
      } else {
        for (int j = 0; j < 8; ++j) tmp[j] = 0;
      }
      *(int4*)&sA[r][c] = *(const int4*)tmp;
    }
  }
  __syncthreads();

  int w = tid >> 6, lane = tid & 63, lr = lane & 15, q = lane >> 4;
  const unsigned short* pB = Bt + (32 * w + lr) * 128 + q * 8;

  bf16x8 B[2][4];
  LDB(pB, B);
  floatx4 acc[4][2];
  for (int mb = 0; mb < 4; ++mb)
    for (int nb = 0; nb < 2; ++nb) acc[mb][nb] = (floatx4){0.f, 0.f, 0.f, 0.f};
  for (int kb = 0; kb < 4; ++kb) {
    int k = kb * 32 + q * 8;
    for (int mb = 0; mb < 4; ++mb) {
      bf16x8 a = *(const bf16x8*)&sA[16 * mb + lr][k];
      acc[mb][0] = __builtin_amdgcn_mfma_f32_16x16x32_bf16(a, B[0][kb], acc[mb][0], 0, 0, 0);
      acc[mb][1] = __builtin_amdgcn_mfma_f32_16x16x32_bf16(a, B[1][kb], acc[mb][1], 0, 0, 0);
    }
  }
  float bv0 = bias[32 * w + lr], bv1 = bias[32 * w + 16 + lr];
  for (int mb = 0; mb < 4; ++mb)
    for (int i = 0; i < 4; ++i) {
      int row = r0 + 16 * mb + 4 * q + i;
      if (row < M) {
        long long base = (long long)row * 128 + 32 * w + lr;
        C[base] = acc[mb][0][i] + bv0;
        C[base + 16] = acc[mb][1][i] + bv1;
      }
    }
}

// ---------------------------------------------------------------------------
// edge_fused: 64 edges/block. Gather [A1|P],[B1|Q] rows; h1=gelu(A1+B1) and
// gate partial dot computed during gather. Then 2 MFMA passes (W2,W3),
// LN, gated atomic scatter. 4 barriers.
// ---------------------------------------------------------------------------
__global__ __launch_bounds__(256, 4) void edge_fused(
    const unsigned short* __restrict__ SrcCat, const unsigned short* __restrict__ DstCat,
    const int* __restrict__ edge_src, const int* __restrict__ edge_dst,
    const unsigned short* __restrict__ wT,
    const float* __restrict__ b2, const float* __restrict__ b3,
    const float* __restrict__ ln_g, const float* __restrict__ ln_b,
    const float* __restrict__ Wg2, const float* __restrict__ bg2,
    float* __restrict__ upd, int E) {
  __shared__ __align__(16) unsigned short sH1[64][136];
  __shared__ __align__(16) unsigned short sH2[64][136];
  __shared__ int sDst[64];
  __shared__ float sGp[64][4];
  __shared__ float sGate[64];
  __shared__ float sR1[4][64];
  __shared__ float sR2[4][64];
  __shared__ float sM[64];
  __shared__ float sRS[64];

  int tid = threadIdx.x;
  int e0 = blockIdx.x * 64;

  {  // gather + h1 + gate partial. 4 threads/row; seg owns cols [32s,32s+32)
    int r = tid >> 2, seg = tid & 3;
    int e = e0 + r;
    int ee = (e < E) ? e : (E - 1);
    int es = edge_src[ee], ed = edge_dst[ee];
    if (seg == 0) sDst[r] = (e < E) ? ed : -1;
    const unsigned short* ps = SrcCat + (long long)es * 256 + seg * 32;
    const unsigned short* pd = DstCat + (long long)ed * 256 + seg * 32;

    int4 sa[4], sb[4], ga[4], gb[4];
    for (int u = 0; u < 4; ++u) {
      sa[u] = ((const int4*)ps)[u];        // A1(+b1) cols
      sb[u] = ((const int4*)pd)[u];        // B1 cols
      ga[u] = ((const int4*)(ps + 128))[u];  // P(+bg1) cols
      gb[u] = ((const int4*)(pd + 128))[u];  // Q cols
    }
    // h1 = gelu(A1 + B1) -> sH1
    for (int u = 0; u < 4; ++u) {
      const unsigned short* av = (const unsigned short*)&sa[u];
      const unsigned short* bv = (const unsigned short*)&sb[u];
      unsigned short outv[8];
      for (int j = 0; j < 8; ++j)
        outv[j] = f2bf(geluf(bf2f(av[j]) + bf2f(bv[j])));
      *(int4*)&sH1[r][seg * 32 + u * 8] = *(const int4*)outv;
    }
    // gate partial: sum_c gelu(P+Q) * Wg2[c]
    float gp = 0.f;
    for (int u = 0; u < 4; ++u) {
      const unsigned short* av = (const unsigned short*)&ga[u];
      const unsigned short* bv = (const unsigned short*)&gb[u];
      float4 w0 = *(const float4*)(Wg2 + seg * 32 + u * 8);
      float4 w1 = *(const float4*)(Wg2 + seg * 32 + u * 8 + 4);
      gp += geluf(bf2f(av[0]) + bf2f(bv[0])) * w0.x;
      gp += geluf(bf2f(av[1]) + bf2f(bv[1])) * w0.y;
      gp += geluf(bf2f(av[2]) + bf2f(bv[2])) * w0.z;
      gp += geluf(bf2f(av[3]) + bf2f(bv[3])) * w0.w;
      gp += geluf(bf2f(av[4]) + bf2f(bv[4])) * w1.x;
      gp += geluf(bf2f(av[5]) + bf2f(bv[5])) * w1.y;
      gp += geluf(bf2f(av[6]) + bf2f(bv[6])) * w1.z;
      gp += geluf(bf2f(av[7]) + bf2f(bv[7])) * w1.w;
    }
    sGp[r][seg] = gp;
  }
  __syncthreads();  // B1: sH1 + sGp + sDst visible

  if (tid < 64) {
    float g = sGp[tid][0] + sGp[tid][1] + sGp[tid][2] + sGp[tid][3] + bg2[0];
    sGate[tid] = 1.f / (1.f + __expf(-g));  // read after B4
  }

  int w = tid >> 6, lane = tid & 63, lr = lane & 15, q = lane >> 4;
  const unsigned short* pB = wT + (32 * w + lr) * 128 + q * 8;

  bf16x8 B[2][4];
  floatx4 acc[4][2];
  auto zacc = [&]() {
    for (int mb = 0; mb < 4; ++mb)
      for (int nb = 0; nb < 2; ++nb) acc[mb][nb] = (floatx4){0.f, 0.f, 0.f, 0.f};
  };
  auto pass = [&](const unsigned short (*Ab)[136]) {
    for (int kb = 0; kb < 4; ++kb) {
      int k = kb * 32 + q * 8;
      for (int mb = 0; mb < 4; ++mb) {
        bf16x8 a = *(const bf16x8*)&Ab[16 * mb + lr][k];
        acc[mb][0] = __builtin_amdgcn_mfma_f32_16x16x32_bf16(a, B[0][kb], acc[mb][0], 0, 0, 0);
        acc[mb][1] = __builtin_amdgcn_mfma_f32_16x16x32_bf16(a, B[1][kb], acc[mb][1], 0, 0, 0);
      }
    }
  };

  // ---- stage 2: h2 = gelu(h1@W2 + b2) -> sH2 ----
  LDB(pB + 4 * 16384, B);
  zacc();
  pass(sH1);
  {
    float bv0 = b2[32 * w + lr], bv1 = b2[32 * w + 16 + lr];
    for (int mb = 0; mb < 4; ++mb)
      for (int i = 0; i < 4; ++i) {
        int r = 16 * mb + 4 * q + i;
        sH2[r][32 * w + lr] = f2bf(geluf(acc[mb][0][i] + bv0));
        sH2[r][32 * w + 16 + lr] = f2bf(geluf(acc[mb][1][i] + bv1));
      }
  }
  __syncthreads();  // B2: sH2 visible

  // ---- stage 3: x = h2@W3 + b3 ; LN partials ----
  LDB(pB + 5 * 16384, B);
  zacc();
  pass(sH2);
  {
    float bv0 = b3[32 * w + lr], bv1 = b3[32 * w + 16 + lr];
    for (int mb = 0; mb < 4; ++mb)
      for (int i = 0; i < 4; ++i) {
        float x0 = acc[mb][0][i] + bv0;
        float x1 = acc[mb][1][i] + bv1;
        acc[mb][0][i] = x0; acc[mb][1][i] = x1;
        float s = x0 + x1, s2 = x0 * x0 + x1 * x1;
        s += __shfl_xor(s, 1); s += __shfl_xor(s, 2);
        s += __shfl_xor(s, 4); s += __shfl_xor(s, 8);
        s2 += __shfl_xor(s2, 1); s2 += __shfl_xor(s2, 2);
        s2 += __shfl_xor(s2, 4); s2 += __shfl_xor(s2, 8);
        if (lr == 0) { sR1[w][16 * mb + 4 * q + i] = s; sR2[w][16 * mb + 4 * q + i] = s2; }
      }
  }
  __syncthreads();  // B3: LN partials visible
  if (tid < 64) {
    float s = sR1[0][tid] + sR1[1][tid] + sR1[2][tid] + sR1[3][tid];
    float s2 = sR2[0][tid] + sR2[1][tid] + sR2[2][tid] + sR2[3][tid];
    float m = s * (1.f / 128.f);
    float v = s2 * (1.f / 128.f) - m * m;
    sM[tid] = m;
    sRS[tid] = rsqrtf(v + LN_EPS);
  }
  __syncthreads();  // B4: stats + sGate visible

  {
    float lg0 = ln_g[32 * w + lr], lg1 = ln_g[32 * w + 16 + lr];
    float lb0 = ln_b[32 * w + lr], lb1 = ln_b[32 * w + 16 + lr];
    for (int mb = 0; mb < 4; ++mb)
      for (int i = 0; i < 4; ++i) {
        int r = 16 * mb + 4 * q + i;
        int dst = sDst[r];
        if (dst >= 0) {
          float m = sM[r], rs = sRS[r], gt = sGate[r];
          float v0 = ((acc[mb][0][i] - m) * rs * lg0 + lb0) * gt;
          float v1 = ((acc[mb][1][i] - m) * rs * lg1 + lb1) * gt;
          float* base = upd + (long long)dst * 128;
          unsafeAtomicAdd(base + 32 * w + lr, v0);
          unsafeAtomicAdd(base + 32 * w + 16 + lr, v1);
        }
      }
  }
}

// ---------------------------------------------------------------------------
extern "C" void kernel_launch(void* const* d_in, const int* in_sizes, int n_in,
                              void* d_out, int out_size, void* d_ws, size_t ws_size,
                              hipStream_t stream) {
  const float* feat   = (const float*)d_in[0];
  const int* edge_src = (const int*)d_in[1];
  const int* edge_dst = (const int*)d_in[2];
  const float* W_src = (const float*)d_in[3];  const float* b_src = (const float*)d_in[4];
  const float* W_dst = (const float*)d_in[5];  const float* b_dst = (const float*)d_in[6];
  const float* W1a = (const float*)d_in[7];    const float* W1b = (const float*)d_in[8];
  const float* b1  = (const float*)d_in[9];
  const float* W2  = (const float*)d_in[10];   const float* b2  = (const float*)d_in[11];
  const float* W3  = (const float*)d_in[12];   const float* b3  = (const float*)d_in[13];
  const float* ln_g = (const float*)d_in[14];  const float* ln_b = (const float*)d_in[15];
  const float* Wg1a = (const float*)d_in[16];  const float* Wg1b = (const float*)d_in[17];
  const float* bg1  = (const float*)d_in[18];
  const float* Wg2  = (const float*)d_in[19];  const float* bg2 = (const float*)d_in[20];
  const float* W_out = (const float*)d_in[21]; const float* b_out = (const float*)d_in[22];

  int N = in_sizes[0] / 128;   // 100000
  int E = in_sizes[1];         // 400000

  // ws layout: [wT 288KB][SrcCat bf16 N*256][DstCat bf16 N*256][upd fp32 N*128]
  char* ws = (char*)d_ws;
  unsigned short* wT = (unsigned short*)ws;
  size_t off = 9 * 16384 * sizeof(unsigned short);
  unsigned short* SrcCat = (unsigned short*)(ws + off);
  off += (size_t)N * 256 * sizeof(unsigned short);
  unsigned short* DstCat = (unsigned short*)(ws + off);
  off += (size_t)N * 256 * sizeof(unsigned short);
  float* upd = (float*)(ws + off);

  (void)hipMemsetAsync(upd, 0, (size_t)N * 128 * sizeof(float), stream);
  prep_weights<<<36, 256, 0, stream>>>(W_src, W_dst, W1a, W1b, W2, W3, Wg1a, Wg1b,
                                       W_out, wT);
  int mtiles = (N + 63) / 64;
  node_fused<<<mtiles, 256, 0, stream>>>(feat, wT, b_src, b_dst, b1, bg1,
                                         SrcCat, DstCat, N);
  edge_fused<<<(E + 63) / 64, 256, 0, stream>>>(SrcCat, DstCat, edge_src, edge_dst,
                                                wT, b2, b3, ln_g, ln_b, Wg2, bg2,
                                                upd, E);
  gemm_out<<<mtiles, 256, 0, stream>>>(upd, wT + 8 * 16384, b_out, (float*)d_out, N);
}

// Round 6
// 454.245 us; speedup vs baseline: 1.2168x; 1.0679x over previous
//
#include <hip/hip_runtime.h>
#include <hip/hip_bf16.h>
#include <math.h>

// MessagePassingLayer on MI355X — round 6.
// vs round 5: (a) gelu/sigmoid use v_exp_f32 (log2e folded into constants)
// + v_rcp_f32 instead of precise f32 division (~15-20 instr -> 7 per gelu;
// 96 gelu/thread in edge_fused). (b) node_fused split over blockIdx.y:
// y=0 src chain, y=1 dst chain — halves per-block critical path.
// Memory ordering kept from round 5 (round 4 showed hoisting loads across
// the gather tripled HBM traffic).

typedef __bf16 bf16x8 __attribute__((ext_vector_type(8)));
typedef float floatx4 __attribute__((ext_vector_type(4)));

#define LN_EPS 1e-5f

__device__ __forceinline__ unsigned short f2bf(float x) {
  unsigned int u = __float_as_uint(x);
  u = u + 0x7fffu + ((u >> 16) & 1u);
  return (unsigned short)(u >> 16);
}

__device__ __forceinline__ float bf2f(unsigned short s) {
  return __uint_as_float(((unsigned int)s) << 16);
}

__device__ __forceinline__ float geluf(float x) {
  // tanh-form gelu = x*sigmoid(u), u = 1.5957691x(1+0.044715x^2).
  // exp(-u) = exp2(-u*log2e): log2e folded into constants.
  // 2.3022080 = 1.5957691*log2e ; 0.1029434 = 0.0713548*log2e.
  float t = x * x;
  float u = x * (2.3022080f + 0.1029434f * t);
  float e = __builtin_amdgcn_exp2f(-u);
  return x * __builtin_amdgcn_rcpf(1.0f + e);
}

__device__ __forceinline__ float sigmoidf_fast(float x) {
  float e = __builtin_amdgcn_exp2f(-1.44269504f * x);
  return __builtin_amdgcn_rcpf(1.0f + e);
}

// ---------------------------------------------------------------------------
// prep: 9 [128,128] fp32 weights -> bf16 [n][k] (transposed). Tiled LDS
// transpose, 36 blocks. slots: 0 WsrcT 1 WdstT 2 W1aT 3 W1bT 4 W2T 5 W3T
// 6 Wg1aT 7 Wg1bT 8 WoutT
// ---------------------------------------------------------------------------
__global__ __launch_bounds__(256) void prep_weights(
    const float* w0, const float* w1, const float* w2, const float* w3,
    const float* w4, const float* w5, const float* w6, const float* w7,
    const float* w8, unsigned short* out) {
  const float* srcs[9] = {w0, w1, w2, w3, w4, w5, w6, w7, w8};
  int m = blockIdx.x >> 2, c = blockIdx.x & 3;
  const float* src = srcs[m] + c * 32 * 128;
  __shared__ unsigned short sT[128][35];
  int tid = threadIdx.x;

  for (int it = 0; it < 4; ++it) {
    int f4 = tid + it * 256;
    float4 v = ((const float4*)src)[f4];
    int krel = f4 >> 5;
    int n0 = (f4 & 31) * 4;
    sT[n0 + 0][krel] = f2bf(v.x);
    sT[n0 + 1][krel] = f2bf(v.y);
    sT[n0 + 2][krel] = f2bf(v.z);
    sT[n0 + 3][krel] = f2bf(v.w);
  }
  __syncthreads();
  unsigned short* dst = out + m * 16384 + c * 32;
  for (int it = 0; it < 2; ++it) {
    int ch = tid + it * 256;
    int n = ch >> 2, kc = (ch & 3) * 8;
    unsigned short tmp[8];
    for (int j = 0; j < 8; ++j) tmp[j] = sT[n][kc + j];
    *(int4*)(dst + n * 128 + kc) = *(const int4*)tmp;
  }
}

// B-fragment loader: wave w, lane (lr,q): rows 32w+lr, 32w+16+lr; cols
// kb*32+q*8..+8 of the [n][k] bf16 matrix.
#define LDB(pB, B)                                              \
  do {                                                          \
    const unsigned short* _p = (pB);                            \
    for (int kb = 0; kb < 4; ++kb) {                            \
      B[0][kb] = *(const bf16x8*)(_p + kb * 32);                \
      B[1][kb] = *(const bf16x8*)(_p + 2048 + kb * 32);         \
    }                                                           \
  } while (0)

// ---------------------------------------------------------------------------
// node_fused: blockIdx.y=0 -> SrcCat = [src_h@W1a+b1 | src_h@Wg1a+bg1]
//             blockIdx.y=1 -> DstCat = [dst_h@W1b    | dst_h@Wg1b    ]
// where src_h = feat@Wsrc+b_src (LDS only), dst_h = feat@Wdst+b_dst.
// ---------------------------------------------------------------------------
__global__ __launch_bounds__(256, 4) void node_fused(
    const float* __restrict__ feat, const unsigned short* __restrict__ wT,
    const float* __restrict__ b_src, const float* __restrict__ b_dst,
    const float* __restrict__ b1, const float* __restrict__ bg1,
    unsigned short* __restrict__ SrcCat, unsigned short* __restrict__ DstCat,
    int M) {
  __shared__ __align__(16) unsigned short sF[64][136];  // feat bf16
  __shared__ __align__(16) unsigned short sT[64][136];  // h tile bf16
  int tid = threadIdx.x;
  int r0 = blockIdx.x * 64;
  int y = blockIdx.y;  // 0=src chain, 1=dst chain

  {  // stage feat
    int r = tid >> 2, seg = tid & 3;
    int row = r0 + r;
    const float* src = feat + (long long)row * 128;
    for (int it = 0; it < 4; ++it) {
      int c = (seg * 4 + it) * 8;
      unsigned short tmp[8];
      if (row < M) {
        float4 f0 = *(const float4*)(src + c);
        float4 f1 = *(const float4*)(src + c + 4);
        tmp[0] = f2bf(f0.x); tmp[1] = f2bf(f0.y); tmp[2] = f2bf(f0.z); tmp[3] = f2bf(f0.w);
        tmp[4] = f2bf(f1.x); tmp[5] = f2bf(f1.y); tmp[6] = f2bf(f1.z); tmp[7] = f2bf(f1.w);
      } else {
        for (int j = 0; j < 8; ++j) tmp[j] = 0;
      }
      *(int4*)&sF[r][c] = *(const int4*)tmp;
    }
  }
  __syncthreads();  // B1: feat staged

  int w = tid >> 6, lane = tid & 63, lr = lane & 15, q = lane >> 4;
  int c0 = 32 * w + lr, c1 = 32 * w + 16 + lr;
  const unsigned short* pB = wT + c0 * 128 + q * 8;

  const unsigned short* wH = pB + (y ? 1 : 0) * 16384;   // Wsrc/Wdst
  const unsigned short* wA = pB + (y ? 3 : 2) * 16384;   // W1a/W1b
  const unsigned short* wG = pB + (y ? 7 : 6) * 16384;   // Wg1a/Wg1b
  unsigned short* Cat = y ? DstCat : SrcCat;
  float hb0 = y ? b_dst[c0] : b_src[c0];
  float hb1 = y ? b_dst[c1] : b_src[c1];
  float ab0 = y ? 0.f : b1[c0];
  float ab1 = y ? 0.f : b1[c1];
  float gb0 = y ? 0.f : bg1[c0];
  float gb1 = y ? 0.f : bg1[c1];

  bf16x8 B[2][4];
  floatx4 acc[4][2];

  auto zacc = [&]() {
    for (int mb = 0; mb < 4; ++mb)
      for (int nb = 0; nb < 2; ++nb) acc[mb][nb] = (floatx4){0.f, 0.f, 0.f, 0.f};
  };
  auto pass = [&](const unsigned short (*Ab)[136]) {
    for (int kb = 0; kb < 4; ++kb) {
      int k = kb * 32 + q * 8;
      for (int mb = 0; mb < 4; ++mb) {
        bf16x8 a = *(const bf16x8*)&Ab[16 * mb + lr][k];
        acc[mb][0] = __builtin_amdgcn_mfma_f32_16x16x32_bf16(a, B[0][kb], acc[mb][0], 0, 0, 0);
        acc[mb][1] = __builtin_amdgcn_mfma_f32_16x16x32_bf16(a, B[1][kb], acc[mb][1], 0, 0, 0);
      }
    }
  };
  auto toGlobal = [&](float bv0, float bv1, int half) {
    for (int mb = 0; mb < 4; ++mb)
      for (int i = 0; i < 4; ++i) {
        int row = r0 + 16 * mb + 4 * q + i;
        if (row < M) {
          long long base = (long long)row * 256 + half + c0;
          Cat[base] = f2bf(acc[mb][0][i] + bv0);
          Cat[base + 16] = f2bf(acc[mb][1][i] + bv1);
        }
      }
  };

  // h = feat@W{src,dst} + b -> sT
  LDB(wH, B); zacc(); pass(sF);
  for (int mb = 0; mb < 4; ++mb)
    for (int i = 0; i < 4; ++i) {
      int r = 16 * mb + 4 * q + i;
      sT[r][c0] = f2bf(acc[mb][0][i] + hb0);
      sT[r][c1] = f2bf(acc[mb][1][i] + hb1);
    }
  __syncthreads();  // B2: h tile visible

  LDB(wA, B); zacc(); pass(sT); toGlobal(ab0, ab1, 0);
  LDB(wG, B); zacc(); pass(sT); toGlobal(gb0, gb1, 128);
}

// ---------------------------------------------------------------------------
// out GEMM: d_out = upd@Wout + b_out (fp32 in, fp32 out)
// ---------------------------------------------------------------------------
__global__ __launch_bounds__(256, 4) void gemm_out(
    const float* __restrict__ A, const unsigned short* __restrict__ Bt,
    const float* __restrict__ bias, float* __restrict__ C, int M) {
  __shared__ __align__(16) unsigned short sA[64][136];
  int tid = threadIdx.x;
  int r0 = blockIdx.x * 64;

  {
    int r = tid >> 2, seg = tid & 3;
    int row = r0 + r;
    const float* src = A + (long long)row * 128;
    for (int it = 0; it < 4; ++it) {
      int c = (seg * 4 + it) * 8;
      unsigned short tmp[8];
      if (row < M) {
        float4 f0 = *(const float4*)(src + c);
        float4 f1 = *(const float4*)(src + c + 4);
        tmp[0] = f2bf(f0.x); tmp[1] = f2bf(f0.y); tmp[2] = f2bf(f0.z); tmp[3] = f2bf(f0.w);
        tmp[4] = f2bf(f1.x); tmp[5] = f2bf(f1.y); tmp[6] = f2bf(f1.z); tmp[7] = f2bf(f1.w);
      } else {
        for (int j = 0; j < 8; ++j) tmp[j] = 0;
      }
      *(int4*)&sA[r][c] = *(const int4*)tmp;
    }
  }
  __syncthreads();

  int w = tid >> 6, lane = tid & 63, lr = lane & 15, q = lane >> 4;
  const unsigned short* pB = Bt + (32 * w + lr) * 128 + q * 8;

  bf16x8 B[2][4];
  LDB(pB, B);
  floatx4 acc[4][2];
  for (int mb = 0; mb < 4; ++mb)
    for (int nb = 0; nb < 2; ++nb) acc[mb][nb] = (floatx4){0.f, 0.f, 0.f, 0.f};
  for (int kb = 0; kb < 4; ++kb) {
    int k = kb * 32 + q * 8;
    for (int mb = 0; mb < 4; ++mb) {
      bf16x8 a = *(const bf16x8*)&sA[16 * mb + lr][k];
      acc[mb][0] = __builtin_amdgcn_mfma_f32_16x16x32_bf16(a, B[0][kb], acc[mb][0], 0, 0, 0);
      acc[mb][1] = __builtin_amdgcn_mfma_f32_16x16x32_bf16(a, B[1][kb], acc[mb][1], 0, 0, 0);
    }
  }
  float bv0 = bias[32 * w + lr], bv1 = bias[32 * w + 16 + lr];
  for (int mb = 0; mb < 4; ++mb)
    for (int i = 0; i < 4; ++i) {
      int row = r0 + 16 * mb + 4 * q + i;
      if (row < M) {
        long long base = (long long)row * 128 + 32 * w + lr;
        C[base] = acc[mb][0][i] + bv0;
        C[base + 16] = acc[mb][1][i] + bv1;
      }
    }
}

// ---------------------------------------------------------------------------
// edge_fused: 64 edges/block. Gather [A1|P],[B1|Q] rows; h1=gelu(A1+B1) and
// gate partial dot computed during gather. Then 2 MFMA passes (W2,W3),
// LN, gated atomic scatter. 4 barriers.
// ---------------------------------------------------------------------------
__global__ __launch_bounds__(256, 4) void edge_fused(
    const unsigned short* __restrict__ SrcCat, const unsigned short* __restrict__ DstCat,
    const int* __restrict__ edge_src, const int* __restrict__ edge_dst,
    const unsigned short* __restrict__ wT,
    const float* __restrict__ b2, const float* __restrict__ b3,
    const float* __restrict__ ln_g, const float* __restrict__ ln_b,
    const float* __restrict__ Wg2, const float* __restrict__ bg2,
    float* __restrict__ upd, int E) {
  __shared__ __align__(16) unsigned short sH1[64][136];
  __shared__ __align__(16) unsigned short sH2[64][136];
  __shared__ int sDst[64];
  __shared__ float sGp[64][4];
  __shared__ float sGate[64];
  __shared__ float sR1[4][64];
  __shared__ float sR2[4][64];
  __shared__ float sM[64];
  __shared__ float sRS[64];

  int tid = threadIdx.x;
  int e0 = blockIdx.x * 64;

  {  // gather + h1 + gate partial. 4 threads/row; seg owns cols [32s,32s+32)
    int r = tid >> 2, seg = tid & 3;
    int e = e0 + r;
    int ee = (e < E) ? e : (E - 1);
    int es = edge_src[ee], ed = edge_dst[ee];
    if (seg == 0) sDst[r] = (e < E) ? ed : -1;
    const unsigned short* ps = SrcCat + (long long)es * 256 + seg * 32;
    const unsigned short* pd = DstCat + (long long)ed * 256 + seg * 32;

    int4 sa[4], sb[4], ga[4], gb[4];
    for (int u = 0; u < 4; ++u) {
      sa[u] = ((const int4*)ps)[u];
      sb[u] = ((const int4*)pd)[u];
      ga[u] = ((const int4*)(ps + 128))[u];
      gb[u] = ((const int4*)(pd + 128))[u];
    }
    for (int u = 0; u < 4; ++u) {
      const unsigned short* av = (const unsigned short*)&sa[u];
      const unsigned short* bv = (const unsigned short*)&sb[u];
      unsigned short outv[8];
      for (int j = 0; j < 8; ++j)
        outv[j] = f2bf(geluf(bf2f(av[j]) + bf2f(bv[j])));
      *(int4*)&sH1[r][seg * 32 + u * 8] = *(const int4*)outv;
    }
    float gp = 0.f;
    for (int u = 0; u < 4; ++u) {
      const unsigned short* av = (const unsigned short*)&ga[u];
      const unsigned short* bv = (const unsigned short*)&gb[u];
      float4 w0 = *(const float4*)(Wg2 + seg * 32 + u * 8);
      float4 w1 = *(const float4*)(Wg2 + seg * 32 + u * 8 + 4);
      gp += geluf(bf2f(av[0]) + bf2f(bv[0])) * w0.x;
      gp += geluf(bf2f(av[1]) + bf2f(bv[1])) * w0.y;
      gp += geluf(bf2f(av[2]) + bf2f(bv[2])) * w0.z;
      gp += geluf(bf2f(av[3]) + bf2f(bv[3])) * w0.w;
      gp += geluf(bf2f(av[4]) + bf2f(bv[4])) * w1.x;
      gp += geluf(bf2f(av[5]) + bf2f(bv[5])) * w1.y;
      gp += geluf(bf2f(av[6]) + bf2f(bv[6])) * w1.z;
      gp += geluf(bf2f(av[7]) + bf2f(bv[7])) * w1.w;
    }
    sGp[r][seg] = gp;
  }
  __syncthreads();  // B1: sH1 + sGp + sDst visible

  if (tid < 64) {
    float g = sGp[tid][0] + sGp[tid][1] + sGp[tid][2] + sGp[tid][3] + bg2[0];
    sGate[tid] = sigmoidf_fast(g);  // read after B4
  }

  int w = tid >> 6, lane = tid & 63, lr = lane & 15, q = lane >> 4;
  const unsigned short* pB = wT + (32 * w + lr) * 128 + q * 8;

  bf16x8 B[2][4];
  floatx4 acc[4][2];
  auto zacc = [&]() {
    for (int mb = 0; mb < 4; ++mb)
      for (int nb = 0; nb < 2; ++nb) acc[mb][nb] = (floatx4){0.f, 0.f, 0.f, 0.f};
  };
  auto pass = [&](const unsigned short (*Ab)[136]) {
    for (int kb = 0; kb < 4; ++kb) {
      int k = kb * 32 + q * 8;
      for (int mb = 0; mb < 4; ++mb) {
        bf16x8 a = *(const bf16x8*)&Ab[16 * mb + lr][k];
        acc[mb][0] = __builtin_amdgcn_mfma_f32_16x16x32_bf16(a, B[0][kb], acc[mb][0], 0, 0, 0);
        acc[mb][1] = __builtin_amdgcn_mfma_f32_16x16x32_bf16(a, B[1][kb], acc[mb][1], 0, 0, 0);
      }
    }
  };

  // ---- stage 2: h2 = gelu(h1@W2 + b2) -> sH2 ----
  LDB(pB + 4 * 16384, B);
  zacc();
  pass(sH1);
  {
    float bv0 = b2[32 * w + lr], bv1 = b2[32 * w + 16 + lr];
    for (int mb = 0; mb < 4; ++mb)
      for (int i = 0; i < 4; ++i) {
        int r = 16 * mb + 4 * q + i;
        sH2[r][32 * w + lr] = f2bf(geluf(acc[mb][0][i] + bv0));
        sH2[r][32 * w + 16 + lr] = f2bf(geluf(acc[mb][1][i] + bv1));
      }
  }
  __syncthreads();  // B2: sH2 visible

  // ---- stage 3: x = h2@W3 + b3 ; LN partials ----
  LDB(pB + 5 * 16384, B);
  zacc();
  pass(sH2);
  {
    float bv0 = b3[32 * w + lr], bv1 = b3[32 * w + 16 + lr];
    for (int mb = 0; mb < 4; ++mb)
      for (int i = 0; i < 4; ++i) {
        float x0 = acc[mb][0][i] + bv0;
        float x1 = acc[mb][1][i] + bv1;
        acc[mb][0][i] = x0; acc[mb][1][i] = x1;
        float s = x0 + x1, s2 = x0 * x0 + x1 * x1;
        s += __shfl_xor(s, 1); s += __shfl_xor(s, 2);
        s += __shfl_xor(s, 4); s += __shfl_xor(s, 8);
        s2 += __shfl_xor(s2, 1); s2 += __shfl_xor(s2, 2);
        s2 += __shfl_xor(s2, 4); s2 += __shfl_xor(s2, 8);
        if (lr == 0) { sR1[w][16 * mb + 4 * q + i] = s; sR2[w][16 * mb + 4 * q + i] = s2; }
      }
  }
  __syncthreads();  // B3: LN partials visible
  if (tid < 64) {
    float s = sR1[0][tid] + sR1[1][tid] + sR1[2][tid] + sR1[3][tid];
    float s2 = sR2[0][tid] + sR2[1][tid] + sR2[2][tid] + sR2[3][tid];
    float m = s * (1.f / 128.f);
    float v = s2 * (1.f / 128.f) - m * m;
    sM[tid] = m;
    sRS[tid] = rsqrtf(v + LN_EPS);
  }
  __syncthreads();  // B4: stats + sGate visible

  {
    float lg0 = ln_g[32 * w + lr], lg1 = ln_g[32 * w + 16 + lr];
    float lb0 = ln_b[32 * w + lr], lb1 = ln_b[32 * w + 16 + lr];
    for (int mb = 0; mb < 4; ++mb)
      for (int i = 0; i < 4; ++i) {
        int r = 16 * mb + 4 * q + i;
        int dst = sDst[r];
        if (dst >= 0) {
          float m = sM[r], rs = sRS[r], gt = sGate[r];
          float v0 = ((acc[mb][0][i] - m) * rs * lg0 + lb0) * gt;
          float v1 = ((acc[mb][1][i] - m) * rs * lg1 + lb1) * gt;
          float* base = upd + (long long)dst * 128;
          unsafeAtomicAdd(base + 32 * w + lr, v0);
          unsafeAtomicAdd(base + 32 * w + 16 + lr, v1);
        }
      }
  }
}

// ---------------------------------------------------------------------------
extern "C" void kernel_launch(void* const* d_in, const int* in_sizes, int n_in,
                              void* d_out, int out_size, void* d_ws, size_t ws_size,
                              hipStream_t stream) {
  const float* feat   = (const float*)d_in[0];
  const int* edge_src = (const int*)d_in[1];
  const int* edge_dst = (const int*)d_in[2];
  const float* W_src = (const float*)d_in[3];  const float* b_src = (const float*)d_in[4];
  const float* W_dst = (const float*)d_in[5];  const float* b_dst = (const float*)d_in[6];
  const float* W1a = (const float*)d_in[7];    const float* W1b = (const float*)d_in[8];
  const float* b1  = (const float*)d_in[9];
  const float* W2  = (const float*)d_in[10];   const float* b2  = (const float*)d_in[11];
  const float* W3  = (const float*)d_in[12];   const float* b3  = (const float*)d_in[13];
  const float* ln_g = (const float*)d_in[14];  const float* ln_b = (const float*)d_in[15];
  const float* Wg1a = (const float*)d_in[16];  const float* Wg1b = (const float*)d_in[17];
  const float* bg1  = (const float*)d_in[18];
  const float* Wg2  = (const float*)d_in[19];  const float* bg2 = (const float*)d_in[20];
  const float* W_out = (const float*)d_in[21]; const float* b_out = (const float*)d_in[22];

  int N = in_sizes[0] / 128;   // 100000
  int E = in_sizes[1];         // 400000

  // ws layout: [wT 288KB][SrcCat bf16 N*256][DstCat bf16 N*256][upd fp32 N*128]
  char* ws = (char*)d_ws;
  unsigned short* wT = (unsigned short*)ws;
  size_t off = 9 * 16384 * sizeof(unsigned short);
  unsigned short* SrcCat = (unsigned short*)(ws + off);
  off += (size_t)N * 256 * sizeof(unsigned short);
  unsigned short* DstCat = (unsigned short*)(ws + off);
  off += (size_t)N * 256 * sizeof(unsigned short);
  float* upd = (float*)(ws + off);

  (void)hipMemsetAsync(upd, 0, (size_t)N * 128 * sizeof(float), stream);
  prep_weights<<<36, 256, 0, stream>>>(W_src, W_dst, W1a, W1b, W2, W3, Wg1a, Wg1b,
                                       W_out, wT);
  int mtiles = (N + 63) / 64;
  node_fused<<<dim3(mtiles, 2), 256, 0, stream>>>(feat, wT, b_src, b_dst, b1, bg1,
                                                  SrcCat, DstCat, N);
  edge_fused<<<(E + 63) / 64, 256, 0, stream>>>(SrcCat, DstCat, edge_src, edge_dst,
                                                wT, b2, b3, ln_g, ln_b, Wg2, bg2,
                                                upd, E);
  gemm_out<<<mtiles, 256, 0, stream>>>(upd, wT + 8 * 16384, b_out, (float*)d_out, N);
}